// Round 3
// baseline (480.879 us; speedup 1.0000x reference)
//
#include <hip/hip_runtime.h>
#include <math.h>

#define BB 4
#define HH 16
#define SS 1024
#define DD 64
#define QT 16     // q rows per block
#define NKW 4     // waves per block, each owns KPW k-columns
#define KPW 256

typedef __attribute__((ext_vector_type(8))) short bf16x8;
typedef __attribute__((ext_vector_type(4))) float f32x4;

static __device__ inline unsigned short f2bf(float f) {
    unsigned int u = __float_as_uint(f);
    u += 0x7fff + ((u >> 16) & 1);   // RNE
    return (unsigned short)(u >> 16);
}
static __device__ inline float bf2f(unsigned short h) {
    return __uint_as_float(((unsigned int)h) << 16);
}

// ---- pre-pass: fp32 -> bf16 for Q and K (row-major unchanged) ----
__global__ __launch_bounds__(256) void convert_qk(const float* __restrict__ q,
                                                  const float* __restrict__ k,
                                                  unsigned short* __restrict__ qb,
                                                  unsigned short* __restrict__ kb) {
    const int idx = blockIdx.x * 256 + threadIdx.x;     // 1,048,576 float4s
    float4 qv = ((const float4*)q)[idx];
    float4 kv = ((const float4*)k)[idx];
    ushort4 qo = make_ushort4(f2bf(qv.x), f2bf(qv.y), f2bf(qv.z), f2bf(qv.w));
    ushort4 ko = make_ushort4(f2bf(kv.x), f2bf(kv.y), f2bf(kv.z), f2bf(kv.w));
    ((ushort4*)qb)[idx] = qo;
    ((ushort4*)kb)[idx] = ko;
}

// ---- pre-pass: V [bh][k][d] fp32 -> Vt [bh][d][k] bf16, LDS-tiled ----
// grid (16 k-tiles, 64 bh), block 256. Coalesced float4 in, ushort4 out.
__global__ __launch_bounds__(256) void transpose_v(const float* __restrict__ v,
                                                   unsigned short* __restrict__ vt) {
    __shared__ float tile[64][68];   // [k_local][d], pitch 68 for alignment
    const int kt = blockIdx.x, bh = blockIdx.y;
    const int k0 = kt * 64;
    const int tid = threadIdx.x;
    const float* vb = v + ((size_t)bh * SS + k0) * DD;

    const int r  = tid >> 4;           // 0..15
    const int c4 = (tid & 15) * 4;     // 0..60
#pragma unroll
    for (int i = 0; i < 4; ++i) {
        const int row = i * 16 + r;
        float4 x = *(const float4*)(vb + (size_t)row * DD + c4);
        *(float4*)&tile[row][c4] = x;
    }
    __syncthreads();
#pragma unroll
    for (int i = 0; i < 4; ++i) {
        const int o  = i * 256 + tid;      // ushort4 index, 1024 total
        const int d  = o >> 4;             // 0..63
        const int kc = (o & 15) * 4;       // 0..60
        ushort4 y = make_ushort4(f2bf(tile[kc + 0][d]), f2bf(tile[kc + 1][d]),
                                 f2bf(tile[kc + 2][d]), f2bf(tile[kc + 3][d]));
        *(ushort4*)(vt + ((size_t)bh * DD + d) * SS + k0 + kc) = y;
    }
}

// ---- main: per block = (b, h, 16-row q-tile); 4 waves split k ----
// QK^T uses A=K, B=Q so C-layout is col=q(row per lane), row=kidx
// -> per lane: ONE q row, 4 consecutive kidx per t-tile (float4 bias!).
__global__ __launch_bounds__(256, 4) void attn_mfma(
    const unsigned short* __restrict__ qb,   // [BH][S][D] bf16
    const unsigned short* __restrict__ kb,   // [BH][S][D] bf16
    const unsigned short* __restrict__ vtb,  // [BH][D][S] bf16
    const float* __restrict__ add_attn,      // [B][S][S]
    const int*   __restrict__ mask,          // [B][S]
    float* __restrict__ out,                 // [BH][S][D]
    float* __restrict__ attn_out)            // [BH][S][S]
{
    const int qt = blockIdx.x, h = blockIdx.y, b = blockIdx.z;
    const int bh = b * HH + h;
    const int tid = threadIdx.x;
    const int wave = tid >> 6;
    const int lane = tid & 63;
    const int col  = lane & 15;
    const int quad = lane >> 4;

    __shared__ __align__(16) unsigned short p_tile[NKW][QT][KPW + 8];
    __shared__ float red_m[NKW][QT];
    __shared__ float red_l[NKW][QT];

    const int q0  = qt * QT;
    const int wk0 = wave * KPW;

    // B-frag for QK^T: Q[q0+col][quad*8+j], reused across all k-tiles
    const unsigned short* qrow = qb + ((size_t)bh * SS + q0 + col) * DD + quad * 8;
    const bf16x8 bq0 = *(const bf16x8*)(qrow);
    const bf16x8 bq1 = *(const bf16x8*)(qrow + 32);

    const unsigned short* kbb = kb + (size_t)bh * SS * DD;
    const float* bias = add_attn + ((size_t)b * SS + q0 + col) * SS;  // this lane's q row
    const int*   mrow = mask + b * SS;

    // ---- QK^T: 16 k-tiles; s[t][r] = score(q=q0+col, kidx=wk0+t*16+quad*4+r) ----
    float s[16][4];
#pragma unroll
    for (int t = 0; t < 16; ++t) {
        const int k0 = wk0 + t * 16;
        const unsigned short* kr = kbb + (size_t)(k0 + col) * DD + quad * 8;
        bf16x8 ak0 = *(const bf16x8*)(kr);
        bf16x8 ak1 = *(const bf16x8*)(kr + 32);
        f32x4 acc = {0.f, 0.f, 0.f, 0.f};
        acc = __builtin_amdgcn_mfma_f32_16x16x32_bf16(ak0, bq0, acc, 0, 0, 0);
        acc = __builtin_amdgcn_mfma_f32_16x16x32_bf16(ak1, bq1, acc, 0, 0, 0);
        const int kbase = k0 + quad * 4;
        const float4 b4 = *(const float4*)(bias + kbase);
        const int4   m4 = *(const int4*)(mrow + kbase);
        s[t][0] = (m4.x == 0) ? -1e9f : acc[0] * 0.125f + b4.x;
        s[t][1] = (m4.y == 0) ? -1e9f : acc[1] * 0.125f + b4.y;
        s[t][2] = (m4.z == 0) ? -1e9f : acc[2] * 0.125f + b4.z;
        s[t][3] = (m4.w == 0) ? -1e9f : acc[3] * 0.125f + b4.w;
    }

    // ---- row max: in-lane over 64 vals, then across quads (xor 16,32) ----
    float mx = s[0][0];
#pragma unroll
    for (int t = 0; t < 16; ++t)
#pragma unroll
        for (int r = 0; r < 4; ++r) mx = fmaxf(mx, s[t][r]);
    mx = fmaxf(mx, __shfl_xor(mx, 16));
    mx = fmaxf(mx, __shfl_xor(mx, 32));
    if (quad == 0) red_m[wave][col] = mx;
    __syncthreads();
    mx = fmaxf(fmaxf(red_m[0][col], red_m[1][col]),
               fmaxf(red_m[2][col], red_m[3][col]));

    // ---- exp + row sum ----
    float ls = 0.f;
#pragma unroll
    for (int t = 0; t < 16; ++t)
#pragma unroll
        for (int r = 0; r < 4; ++r) {
            float e = __expf(s[t][r] - mx);
            s[t][r] = e;
            ls += e;
        }
    ls += __shfl_xor(ls, 16);
    ls += __shfl_xor(ls, 32);
    if (quad == 0) red_l[wave][col] = ls;
    __syncthreads();
    const float inv = 1.0f / (red_l[0][col] + red_l[1][col] +
                              red_l[2][col] + red_l[3][col]);

    // ---- normalize -> p_tile[wave][q][k_local] as bf16 (ushort4 writes) ----
#pragma unroll
    for (int t = 0; t < 16; ++t) {
        ushort4 pk = make_ushort4(f2bf(s[t][0] * inv), f2bf(s[t][1] * inv),
                                  f2bf(s[t][2] * inv), f2bf(s[t][3] * inv));
        *(ushort4*)&p_tile[wave][col][t * 16 + quad * 4] = pk;
    }
    __syncthreads();

    // ---- PV: A = p_tile (wave-local, q=col rows), B = Vt contiguous 16B ----
    const unsigned short* vt = vtb + (size_t)bh * DD * SS;
    f32x4 oacc[4];
#pragma unroll
    for (int dc = 0; dc < 4; ++dc) oacc[dc] = (f32x4){0.f, 0.f, 0.f, 0.f};
#pragma unroll
    for (int c = 0; c < 8; ++c) {
        bf16x8 ap = *(const bf16x8*)(&p_tile[wave][col][c * 32 + quad * 8]);
#pragma unroll
        for (int dc = 0; dc < 4; ++dc) {
            const unsigned short* vr =
                vt + (size_t)(dc * 16 + col) * SS + wk0 + c * 32 + quad * 8;
            bf16x8 bv = *(const bf16x8*)(vr);
            oacc[dc] = __builtin_amdgcn_mfma_f32_16x16x32_bf16(ap, bv, oacc[dc], 0, 0, 0);
        }
    }

    // ---- attn write: coalesced float4 stores from p_tile (bf16->f32) ----
    float* ab = attn_out + ((size_t)bh * SS + q0) * SS;
#pragma unroll
    for (int i = 0; i < 16; ++i) {
        const int o  = i * 256 + tid;      // float4 index in 16x1024 tile
        const int qr = o >> 8;
        const int cc = (o & 255) * 4;
        const int w  = cc >> 8;
        const int cl = cc & 255;
        ushort4 p4 = *(const ushort4*)&p_tile[w][qr][cl];
        float4 f;
        f.x = bf2f(p4.x); f.y = bf2f(p4.y); f.z = bf2f(p4.z); f.w = bf2f(p4.w);
        *(float4*)(ab + (size_t)qr * SS + cc) = f;
    }
    __syncthreads();   // all p_tile reads done -> safe to overlay o_part

    // ---- overlay o_part onto p_tile memory (per-wave region) ----
    float* opw = (float*)&p_tile[wave][0][0];   // 16x64 floats per wave
#pragma unroll
    for (int dc = 0; dc < 4; ++dc)
#pragma unroll
        for (int r = 0; r < 4; ++r)
            opw[(quad * 4 + r) * 64 + dc * 16 + col] = oacc[dc][r];
    __syncthreads();

    // ---- cross-wave sum + out write (float4) ----
    {
        const int qr = tid >> 4, d4 = (tid & 15) * 4;
        float4 sum;
        const float* p0 = (const float*)&p_tile[0][0][0] + qr * 64 + d4;
        const float* p1 = (const float*)&p_tile[1][0][0] + qr * 64 + d4;
        const float* p2 = (const float*)&p_tile[2][0][0] + qr * 64 + d4;
        const float* p3 = (const float*)&p_tile[3][0][0] + qr * 64 + d4;
        sum.x = p0[0] + p1[0] + p2[0] + p3[0];
        sum.y = p0[1] + p1[1] + p2[1] + p3[1];
        sum.z = p0[2] + p1[2] + p2[2] + p3[2];
        sum.w = p0[3] + p1[3] + p2[3] + p3[3];
        *(float4*)(out + ((size_t)bh * SS + q0 + qr) * DD + d4) = sum;
    }
}

extern "C" void kernel_launch(void* const* d_in, const int* in_sizes, int n_in,
                              void* d_out, int out_size, void* d_ws, size_t ws_size,
                              hipStream_t stream) {
    const float* q        = (const float*)d_in[0];
    const float* k        = (const float*)d_in[1];
    const float* v        = (const float*)d_in[2];
    const float* add_attn = (const float*)d_in[3];
    const int*   mask     = (const int*)d_in[4];

    float* out      = (float*)d_out;
    float* attn_out = (float*)d_out + (size_t)BB * HH * SS * DD;

    const size_t nelem = (size_t)BB * HH * SS * DD;     // 4,194,304
    unsigned short* qb  = (unsigned short*)d_ws;
    unsigned short* kbb = qb + nelem;
    unsigned short* vtb = kbb + nelem;

    convert_qk<<<dim3(nelem / 4 / 256), dim3(256), 0, stream>>>(q, k, qb, kbb);
    transpose_v<<<dim3(16, 64), dim3(256), 0, stream>>>(v, vtb);

    dim3 grid(SS / QT, HH, BB);
    attn_mfma<<<grid, dim3(256), 0, stream>>>(qb, kbb, vtb, add_attn, mask, out, attn_out);
}